// Round 1
// baseline (2373.678 us; speedup 1.0000x reference)
//
#include <hip/hip_runtime.h>
#include <math.h>

#define HD 128
#define NEG_SLOPE 0.2f
#define RPB 16

// ---- monotone float<->uint encoding for atomicMax on floats ----
static __device__ __forceinline__ unsigned fenc(float f) {
    unsigned u = __float_as_uint(f);
    return (u & 0x80000000u) ? ~u : (u | 0x80000000u);
}
static __device__ __forceinline__ float fdec(unsigned u) {
    return __uint_as_float((u & 0x80000000u) ? (u & 0x7FFFFFFFu) : ~u);
}

// ---- degree counts ----
__global__ void k_count(const int* __restrict__ row, const int* __restrict__ col,
                        float* __restrict__ Dc, float* __restrict__ Bc, int E) {
    int e = blockIdx.x * blockDim.x + threadIdx.x;
    if (e < E) {
        atomicAdd(&Dc[row[e]], 1.0f);
        atomicAdd(&Bc[col[e]], 1.0f);
    }
}

__global__ void k_inv(float* __restrict__ D, float* __restrict__ B, int n) {
    int i = blockIdx.x * blockDim.x + threadIdx.x;
    if (i < n) {
        float d = D[i]; D[i] = d > 0.f ? 1.f / d : 0.f;
        float b = B[i]; B[i] = b > 0.f ? 1.f / b : 0.f;
    }
}

// ---- GEMM: xw = in @ W  (W resident in LDS), fused sI = xw@a_i, sJ = xw@a_j ----
__global__ __launch_bounds__(128) void k_gemm(const float* __restrict__ in,
                                              const float* __restrict__ W,
                                              const float* __restrict__ att,
                                              float* __restrict__ xw,
                                              float* __restrict__ sI,
                                              float* __restrict__ sJ, int nrows) {
    __shared__ float Wl[HD * HD];
    __shared__ float xs[HD];
    __shared__ float red[4];
    int t = threadIdx.x;
    for (int i = t; i < HD * HD; i += 128) Wl[i] = W[i];
    float ai = att[t];
    float aj = att[HD + t];
    __syncthreads();
    int r0 = blockIdx.x * RPB;
    int r1 = min(r0 + RPB, nrows);
    for (int n = r0; n < r1; ++n) {
        xs[t] = in[n * HD + t];
        __syncthreads();
        float acc = 0.f;
        #pragma unroll
        for (int k = 0; k < HD; ++k) acc += xs[k] * Wl[k * HD + t];
        xw[n * HD + t] = acc;
        float p = acc * ai, q = acc * aj;
        #pragma unroll
        for (int o = 32; o > 0; o >>= 1) {
            p += __shfl_down(p, o);
            q += __shfl_down(q, o);
        }
        if ((t & 63) == 0) { red[(t >> 6) * 2] = p; red[(t >> 6) * 2 + 1] = q; }
        __syncthreads();
        if (t == 0) { sI[n] = red[0] + red[2]; sJ[n] = red[1] + red[3]; }
    }
}

// ---- logits + segment max over col ----
__global__ void k_logit(const float* __restrict__ sI, const float* __restrict__ sJ,
                        const int* __restrict__ row, const int* __restrict__ col,
                        float* __restrict__ logits, unsigned* __restrict__ menc, int E) {
    int e = blockIdx.x * blockDim.x + threadIdx.x;
    if (e >= E) return;
    float l = sI[row[e]] + sJ[col[e]];
    l = (l >= 0.f) ? l : NEG_SLOPE * l;
    logits[e] = l;
    atomicMax(&menc[col[e]], fenc(l));
}

// ---- exp + segment sum over col (e_val overwrites logits) ----
__global__ void k_exp(float* __restrict__ logits, const unsigned* __restrict__ menc,
                      const int* __restrict__ col, float* __restrict__ s, int E) {
    int e = blockIdx.x * blockDim.x + threadIdx.x;
    if (e >= E) return;
    int c = col[e];
    float ev = expf(logits[e] - fdec(menc[c]));
    logits[e] = ev;
    atomicAdd(&s[c], ev);
}

// ---- scatter 1: edge_feat[col] += alpha * xw[row] ----
__global__ __launch_bounds__(256) void k_sc1(const float* __restrict__ ev, const float* __restrict__ s,
                                             const int* __restrict__ row, const int* __restrict__ col,
                                             const float* __restrict__ xw, float* __restrict__ ef, int E) {
    int e = blockIdx.x * 2 + (threadIdx.x >> 7);
    if (e >= E) return;
    int h = threadIdx.x & (HD - 1);
    int c = col[e];
    float a = ev[e] / (s[c] + 1e-16f);
    atomicAdd(&ef[c * HD + h], a * xw[row[e] * HD + h]);
}

// ---- scatter 2: acc[row] += alpha * Binv[col] * edge_feat[col] ----
__global__ __launch_bounds__(256) void k_sc2(const float* __restrict__ ev, const float* __restrict__ s,
                                             const float* __restrict__ Binv,
                                             const int* __restrict__ row, const int* __restrict__ col,
                                             const float* __restrict__ ef, float* __restrict__ acc, int E) {
    int e = blockIdx.x * 2 + (threadIdx.x >> 7);
    if (e >= E) return;
    int h = threadIdx.x & (HD - 1);
    int c = col[e];
    float a = ev[e] / (s[c] + 1e-16f) * Binv[c];
    atomicAdd(&acc[row[e] * HD + h], a * ef[c * HD + h]);
}

// ---- finals ----
__global__ void k_fin1(const float* __restrict__ acc, const float* __restrict__ Dinv,
                       const float* __restrict__ b, const float* __restrict__ pa,
                       float* __restrict__ out, int NH) {
    int i = blockIdx.x * blockDim.x + threadIdx.x;
    if (i >= NH) return;
    int n = i >> 7, h = i & (HD - 1);
    float v = Dinv[n] * acc[i] + b[h];
    out[i] = v >= 0.f ? v : pa[0] * v;
}

__global__ void k_fin2(const float* __restrict__ acc, const float* __restrict__ Dinv,
                       const float* __restrict__ b, const float* __restrict__ x,
                       const float* __restrict__ pa, float* __restrict__ out, int NH) {
    int i = blockIdx.x * blockDim.x + threadIdx.x;
    if (i >= NH) return;
    int n = i >> 7, h = i & (HD - 1);
    float v = Dinv[n] * acc[i] + b[h] + x[i];
    out[i] = v >= 0.f ? v : pa[0] * v;
}

extern "C" void kernel_launch(void* const* d_in, const int* in_sizes, int n_in,
                              void* d_out, int out_size, void* d_ws, size_t ws_size,
                              hipStream_t stream) {
    const float* x    = (const float*)d_in[0];
    const int*   hei  = (const int*)d_in[1];
    const float* W1   = (const float*)d_in[2];
    const float* att1 = (const float*)d_in[3];
    const float* b1   = (const float*)d_in[4];
    const float* W2   = (const float*)d_in[5];
    const float* att2 = (const float*)d_in[6];
    const float* b2   = (const float*)d_in[7];
    const float* pa   = (const float*)d_in[8];

    const int NH = in_sizes[0];          // N * 128
    const int Nn = NH / HD;              // N
    const int E  = in_sizes[1] / 2;
    const int* row = hei;
    const int* col = hei + E;

    float* ws = (float*)d_ws;
    float*    xw     = ws;                    // NH
    float*    acc    = ws + (size_t)NH;       // NH
    float*    ef     = ws + (size_t)2 * NH;   // NH
    float*    logits = ws + (size_t)3 * NH;   // E (becomes e_val in place)
    unsigned* menc   = (unsigned*)(logits + E);            // Nn
    float*    ssum   = (float*)(menc + Nn);                // Nn
    float*    Dinv   = ssum + Nn;                          // Nn
    float*    Binv   = Dinv + Nn;                          // Nn
    float*    sI     = Binv + Nn;                          // Nn
    float*    sJ     = sI + Nn;                            // Nn

    float* out = (float*)d_out;

    const int TB = 256;
    dim3 blk(TB);
    dim3 gE((E + TB - 1) / TB);
    dim3 gN((Nn + TB - 1) / TB);
    dim3 gNH((NH + TB - 1) / TB);
    dim3 gSc((E + 1) / 2);               // 2 edges per 256-thread block
    dim3 gGemm((Nn + RPB - 1) / RPB);

    // degree counts (shared by both layers)
    hipMemsetAsync(Dinv, 0, (size_t)2 * Nn * sizeof(float), stream);
    k_count<<<gE, blk, 0, stream>>>(row, col, Dinv, Binv, E);
    k_inv<<<gN, blk, 0, stream>>>(Dinv, Binv, Nn);

    // ---------------- layer 1 ----------------
    k_gemm<<<gGemm, dim3(128), 0, stream>>>(x, W1, att1, xw, sI, sJ, Nn);
    hipMemsetAsync(menc, 0, (size_t)2 * Nn * sizeof(float), stream);   // menc + ssum
    k_logit<<<gE, blk, 0, stream>>>(sI, sJ, row, col, logits, menc, E);
    k_exp<<<gE, blk, 0, stream>>>(logits, menc, col, ssum, E);
    hipMemsetAsync(ef, 0, (size_t)NH * sizeof(float), stream);
    k_sc1<<<gSc, blk, 0, stream>>>(logits, ssum, row, col, xw, ef, E);
    hipMemsetAsync(acc, 0, (size_t)NH * sizeof(float), stream);
    k_sc2<<<gSc, blk, 0, stream>>>(logits, ssum, Binv, row, col, ef, acc, E);
    k_fin1<<<gNH, blk, 0, stream>>>(acc, Dinv, b1, pa, out, NH);  // h1 -> d_out

    // ---------------- layer 2 ----------------
    k_gemm<<<gGemm, dim3(128), 0, stream>>>(out, W2, att2, xw, sI, sJ, Nn);
    hipMemsetAsync(menc, 0, (size_t)2 * Nn * sizeof(float), stream);
    k_logit<<<gE, blk, 0, stream>>>(sI, sJ, row, col, logits, menc, E);
    k_exp<<<gE, blk, 0, stream>>>(logits, menc, col, ssum, E);
    hipMemsetAsync(ef, 0, (size_t)NH * sizeof(float), stream);
    k_sc1<<<gSc, blk, 0, stream>>>(logits, ssum, row, col, xw, ef, E);
    hipMemsetAsync(acc, 0, (size_t)NH * sizeof(float), stream);
    k_sc2<<<gSc, blk, 0, stream>>>(logits, ssum, Binv, row, col, ef, acc, E);
    k_fin2<<<gNH, blk, 0, stream>>>(acc, Dinv, b2, x, pa, out, NH);
}

// Round 3
// 766.237 us; speedup vs baseline: 3.0978x; 3.0978x over previous
//
#include <hip/hip_runtime.h>
#include <math.h>

#define HD 128
#define NEG_SLOPE 0.2f

// ============================ CSR build ============================

__global__ void k_hist(const int* __restrict__ row, const int* __restrict__ col,
                       int* __restrict__ hr, int* __restrict__ hc, int E) {
    int e = blockIdx.x * blockDim.x + threadIdx.x;
    if (e < E) {
        atomicAdd(&hr[row[e]], 1);
        atomicAdd(&hc[col[e]], 1);
    }
}

__device__ __forceinline__ int blk_exscan(int v, int t, int* ws) {
    int inc = v;
    #pragma unroll
    for (int o = 1; o < 64; o <<= 1) {
        int u = __shfl_up(inc, o);
        if ((t & 63) >= o) inc += u;
    }
    int w = t >> 6;
    if ((t & 63) == 63) ws[w] = inc;
    __syncthreads();
    int off = 0;
    for (int i = 0; i < w; ++i) off += ws[i];
    return off + inc - v;
}

__global__ void k_scan1(const int* __restrict__ h, int* __restrict__ part, int n) {
    __shared__ int ws[8];
    int t = threadIdx.x;
    int i = blockIdx.x * 256 + t;
    int v = (i < n) ? h[i] : 0;
    #pragma unroll
    for (int o = 32; o > 0; o >>= 1) v += __shfl_down(v, o);
    if ((t & 63) == 0) ws[t >> 6] = v;
    __syncthreads();
    if (t == 0) part[blockIdx.x] = ws[0] + ws[1] + ws[2] + ws[3];
}

__global__ void k_scan2(int* __restrict__ part, int nb) {
    __shared__ int ws[8];
    int t = threadIdx.x;
    int v = (t < nb) ? part[t] : 0;
    int e = blk_exscan(v, t, ws);
    if (t < nb) part[t] = e;
}

__global__ void k_scan3(const int* __restrict__ h, const int* __restrict__ part,
                        int* __restrict__ ptr, int n) {
    __shared__ int ws[8];
    int t = threadIdx.x;
    int i = blockIdx.x * 256 + t;
    int v = (i < n) ? h[i] : 0;
    int e = blk_exscan(v, t, ws);
    if (i <= n) ptr[i] = part[blockIdx.x] + e;
}

__global__ void k_fill(const int* __restrict__ row, const int* __restrict__ col,
                       const int* __restrict__ cptr, const int* __restrict__ rptr,
                       int* __restrict__ cntc, int* __restrict__ cntr,
                       int* __restrict__ crows, int* __restrict__ rcols,
                       int* __restrict__ rcpos, int E) {
    int e = blockIdx.x * blockDim.x + threadIdx.x;
    if (e >= E) return;
    int r = row[e], c = col[e];
    int cp = cptr[c] + atomicAdd(&cntc[c], 1);
    int rp = rptr[r] + atomicAdd(&cntr[r], 1);
    crows[cp] = r;
    rcols[rp] = c;
    rcpos[rp] = cp;
}

// ============================ GEMM ============================
// 64-row tile, full 128 cols, K tiled 2x64. 256 threads; thread = 4 rows x 8 cols.
// xs is x-tile transposed [k][r] with XOR swizzle on the row-quad index.

__global__ __launch_bounds__(256) void k_gemm(const float* __restrict__ in,
                                              const float* __restrict__ W,
                                              float* __restrict__ xw,
                                              int nrows, int ntiles) {
    __shared__ float xs[128 * 64];
    __shared__ float Wl[64 * 128];
    const int t = threadIdx.x;
    const int rg = t & 15;   // row group: rows 4*rg .. 4*rg+3
    const int cg = t >> 4;   // col group: cols 8*cg .. 8*cg+7

    for (int tile = blockIdx.x; tile < ntiles; tile += gridDim.x) {
        const int r0 = tile << 6;
        __syncthreads();   // protect xs/Wl against previous iteration's readers
        // stage x tile transposed+swizzled: element (k, r) -> xs[k*64 + (((r>>2)^((k>>2)&15))<<2 | (r&3))]
        #pragma unroll
        for (int it = 0; it < 8; ++it) {
            int q = t + (it << 8);      // 0..2047
            int r = q >> 5;             // 0..63
            int kq = q & 31;            // k-quad 0..31
            int gr = r0 + r;
            float4 v = make_float4(0.f, 0.f, 0.f, 0.f);
            if (gr < nrows) v = *(const float4*)&in[(size_t)gr * HD + (kq << 2)];
            int rq = r >> 2, rl = r & 3;
            const float* pv = (const float*)&v;
            int fk = kq & 15;
            #pragma unroll
            for (int j = 0; j < 4; ++j) {
                int k = (kq << 2) + j;
                xs[(k << 6) + (((rq ^ fk) << 2) | rl)] = pv[j];
            }
        }
        float acc[4][8];
        #pragma unroll
        for (int i = 0; i < 4; ++i)
            #pragma unroll
            for (int j = 0; j < 8; ++j) acc[i][j] = 0.f;

        for (int kt = 0; kt < 2; ++kt) {
            __syncthreads();   // previous k-loop (or xs staging) done before Wl overwrite
            #pragma unroll
            for (int it = 0; it < 8; ++it) {
                int q = (t + (it << 8)) << 2;
                *(float4*)&Wl[q] = *(const float4*)&W[(size_t)(kt << 6) * HD + q];
            }
            __syncthreads();
            #pragma unroll 8
            for (int kk = 0; kk < 64; ++kk) {
                int fk = kk >> 2;   // ((kt*64+kk)>>2)&15 == kk>>2
                float4 a  = *(const float4*)&xs[(((kt << 6) + kk) << 6) + ((rg ^ fk) << 2)];
                float4 b0 = *(const float4*)&Wl[(kk << 7) + (cg << 3)];
                float4 b1 = *(const float4*)&Wl[(kk << 7) + (cg << 3) + 4];
                const float* ap = (const float*)&a;
                const float* b0p = (const float*)&b0;
                const float* b1p = (const float*)&b1;
                #pragma unroll
                for (int i = 0; i < 4; ++i) {
                    #pragma unroll
                    for (int j = 0; j < 4; ++j) {
                        acc[i][j]     += ap[i] * b0p[j];
                        acc[i][j + 4] += ap[i] * b1p[j];
                    }
                }
            }
        }
        #pragma unroll
        for (int i = 0; i < 4; ++i) {
            int gr = r0 + (rg << 2) + i;
            if (gr < nrows) {
                float4 o0 = make_float4(acc[i][0], acc[i][1], acc[i][2], acc[i][3]);
                float4 o1 = make_float4(acc[i][4], acc[i][5], acc[i][6], acc[i][7]);
                *(float4*)&xw[(size_t)gr * HD + (cg << 3)]     = o0;
                *(float4*)&xw[(size_t)gr * HD + (cg << 3) + 4] = o1;
            }
        }
    }
}

// ============================ attention scores ============================
// sI[n] = xw[n]·att[0:128], sJ[n] = xw[n]·att[128:256]; one wave per row.

__global__ __launch_bounds__(256) void k_att(const float* __restrict__ xw,
                                             const float* __restrict__ att,
                                             float* __restrict__ sI, float* __restrict__ sJ, int n) {
    int r = blockIdx.x * 4 + (threadIdx.x >> 6);
    if (r >= n) return;
    int l = threadIdx.x & 63;
    float2 v  = *(const float2*)&xw[(size_t)r * HD + 2 * l];
    float2 ai = *(const float2*)&att[2 * l];
    float2 aj = *(const float2*)&att[HD + 2 * l];
    float p = v.x * ai.x + v.y * ai.y;
    float q = v.x * aj.x + v.y * aj.y;
    #pragma unroll
    for (int o = 32; o > 0; o >>= 1) { p += __shfl_down(p, o); q += __shfl_down(q, o); }
    if (l == 0) { sI[r] = p; sJ[r] = q; }
}

// ============================ per-segment softmax (col) ============================
// one lane per hyperedge; alpha indexed by col-CSR position, fully normalized.

__global__ void k_soft(const float* __restrict__ sI, const float* __restrict__ sJ,
                       const int* __restrict__ cptr, const int* __restrict__ crows,
                       float* __restrict__ alpha, int n) {
    int c = blockIdx.x * blockDim.x + threadIdx.x;
    if (c >= n) return;
    int p0 = cptr[c], p1 = cptr[c + 1];
    if (p0 == p1) return;
    float sj = sJ[c];
    float m = -1e30f;
    for (int p = p0; p < p1; ++p) {
        float l = sI[crows[p]] + sj;
        l = (l >= 0.f) ? l : NEG_SLOPE * l;
        alpha[p] = l;
        m = fmaxf(m, l);
    }
    float s = 0.f;
    for (int p = p0; p < p1; ++p) {
        float ev = __expf(alpha[p] - m);
        alpha[p] = ev;
        s += ev;
    }
    float si = 1.f / (s + 1e-16f);
    for (int p = p0; p < p1; ++p) alpha[p] *= si;
}

// ============================ edge_feat = Binv * sum alpha*xw[row] ============================
// one wave per hyperedge c; lane covers 2 features.

__global__ __launch_bounds__(256) void k_ef(const int* __restrict__ cptr, const int* __restrict__ crows,
                                            const float* __restrict__ alpha, const float* __restrict__ xw,
                                            float* __restrict__ ef, int n) {
    int c = blockIdx.x * 4 + (threadIdx.x >> 6);
    if (c >= n) return;
    int l = threadIdx.x & 63;
    int p0 = cptr[c], p1 = cptr[c + 1];
    float ax = 0.f, ay = 0.f;
    for (int p = p0; p < p1; ++p) {
        float a = alpha[p];
        float2 v = *(const float2*)&xw[(size_t)crows[p] * HD + 2 * l];
        ax += a * v.x; ay += a * v.y;
    }
    float binv = (p1 > p0) ? 1.f / (float)(p1 - p0) : 0.f;
    *(float2*)&ef[(size_t)c * HD + 2 * l] = make_float2(ax * binv, ay * binv);
}

// ============================ out = prelu(Dinv * sum alpha*ef[col] + b (+resid)) ============================

__global__ __launch_bounds__(256) void k_out(const int* __restrict__ rptr, const int* __restrict__ rcols,
                                             const int* __restrict__ rcpos, const float* __restrict__ alpha,
                                             const float* __restrict__ ef, const float* __restrict__ bias,
                                             const float* __restrict__ resid, const float* __restrict__ pa,
                                             float* __restrict__ out, int n) {
    int nd = blockIdx.x * 4 + (threadIdx.x >> 6);
    if (nd >= n) return;
    int l = threadIdx.x & 63;
    int p0 = rptr[nd], p1 = rptr[nd + 1];
    float ax = 0.f, ay = 0.f;
    for (int p = p0; p < p1; ++p) {
        float a = alpha[rcpos[p]];
        float2 v = *(const float2*)&ef[(size_t)rcols[p] * HD + 2 * l];
        ax += a * v.x; ay += a * v.y;
    }
    float dinv = (p1 > p0) ? 1.f / (float)(p1 - p0) : 0.f;
    int h = 2 * l;
    float vx = dinv * ax + bias[h];
    float vy = dinv * ay + bias[h + 1];
    size_t idx = (size_t)nd * HD + h;
    if (resid) { vx += resid[idx]; vy += resid[idx + 1]; }
    float s = pa[0];
    vx = vx >= 0.f ? vx : s * vx;
    vy = vy >= 0.f ? vy : s * vy;
    out[idx] = vx; out[idx + 1] = vy;
}

// ============================ launch ============================

extern "C" void kernel_launch(void* const* d_in, const int* in_sizes, int n_in,
                              void* d_out, int out_size, void* d_ws, size_t ws_size,
                              hipStream_t stream) {
    const float* x    = (const float*)d_in[0];
    const int*   hei  = (const int*)d_in[1];
    const float* W1   = (const float*)d_in[2];
    const float* att1 = (const float*)d_in[3];
    const float* b1   = (const float*)d_in[4];
    const float* W2   = (const float*)d_in[5];
    const float* att2 = (const float*)d_in[6];
    const float* b2   = (const float*)d_in[7];
    const float* pa   = (const float*)d_in[8];

    const int NH = in_sizes[0];
    const int Nn = NH / HD;
    const int E  = in_sizes[1] / 2;
    const int* row = hei;
    const int* col = hei + E;
    float* out = (float*)d_out;

    // workspace carve-up
    char* ws = (char*)d_ws;
    float* xw      = (float*)ws;                       ws += (size_t)NH * 4;
    float* ef      = (float*)ws;                       ws += (size_t)NH * 4;
    float* alpha   = (float*)ws;                       ws += (size_t)E * 4;
    int*   crows   = (int*)ws;                         ws += (size_t)E * 4;
    int*   rcols   = (int*)ws;                         ws += (size_t)E * 4;
    int*   rcpos   = (int*)ws;                         ws += (size_t)E * 4;
    int*   cptr    = (int*)ws;                         ws += (size_t)(Nn + 1) * 4;
    int*   rptr    = (int*)ws;                         ws += (size_t)(Nn + 1) * 4;
    int*   hists   = (int*)ws;                         ws += (size_t)4 * Nn * 4;  // hr, hc, cntr, cntc
    int*   part    = (int*)ws;                         ws += 512 * 4;
    float* sI      = (float*)ws;                       ws += (size_t)Nn * 4;
    float* sJ      = (float*)ws;                       ws += (size_t)Nn * 4;
    int* hr = hists, *hc = hists + Nn, *cntr = hists + 2 * Nn, *cntc = hists + 3 * Nn;

    const int TB = 256;
    dim3 blk(TB);
    dim3 gE((E + TB - 1) / TB);
    dim3 gN((Nn + TB - 1) / TB);
    dim3 gW4((Nn + 3) / 4);              // wave-per-item kernels
    const int nb = (Nn + 1 + 255) / 256; // scan blocks (covers N+1 outputs)
    const int ntiles = (Nn + 63) >> 6;
    dim3 gGemm(512);

    // ---- CSR build (shared by both layers) ----
    hipMemsetAsync(hists, 0, (size_t)4 * Nn * 4, stream);
    k_hist<<<gE, blk, 0, stream>>>(row, col, hr, hc, E);
    // scan col
    k_scan1<<<nb, blk, 0, stream>>>(hc, part, Nn);
    k_scan2<<<1, 512, 0, stream>>>(part, nb);
    k_scan3<<<nb, blk, 0, stream>>>(hc, part, cptr, Nn);
    // scan row
    k_scan1<<<nb, blk, 0, stream>>>(hr, part, Nn);
    k_scan2<<<1, 512, 0, stream>>>(part, nb);
    k_scan3<<<nb, blk, 0, stream>>>(hr, part, rptr, Nn);
    k_fill<<<gE, blk, 0, stream>>>(row, col, cptr, rptr, cntc, cntr, crows, rcols, rcpos, E);

    // ---- layer 1 ----
    k_gemm<<<gGemm, blk, 0, stream>>>(x, W1, xw, Nn, ntiles);
    k_att<<<gW4, blk, 0, stream>>>(xw, att1, sI, sJ, Nn);
    k_soft<<<gN, blk, 0, stream>>>(sI, sJ, cptr, crows, alpha, Nn);
    k_ef<<<gW4, blk, 0, stream>>>(cptr, crows, alpha, xw, ef, Nn);
    k_out<<<gW4, blk, 0, stream>>>(rptr, rcols, rcpos, alpha, ef, b1, nullptr, pa, out, Nn);

    // ---- layer 2 (input = d_out, residual = x) ----
    k_gemm<<<gGemm, blk, 0, stream>>>(out, W2, xw, Nn, ntiles);
    k_att<<<gW4, blk, 0, stream>>>(xw, att2, sI, sJ, Nn);
    k_soft<<<gN, blk, 0, stream>>>(sI, sJ, cptr, crows, alpha, Nn);
    k_ef<<<gW4, blk, 0, stream>>>(cptr, crows, alpha, xw, ef, Nn);
    k_out<<<gW4, blk, 0, stream>>>(rptr, rcols, rcpos, alpha, ef, b2, x, pa, out, Nn);
}

// Round 4
// 733.096 us; speedup vs baseline: 3.2379x; 1.0452x over previous
//
#include <hip/hip_runtime.h>
#include <math.h>

#define HD 128
#define NEG_SLOPE 0.2f

// ============================ CSR build ============================

__global__ void k_hist(const int* __restrict__ row, const int* __restrict__ col,
                       int* __restrict__ hr, int* __restrict__ hc, int E) {
    int e = blockIdx.x * blockDim.x + threadIdx.x;
    if (e < E) {
        atomicAdd(&hr[row[e]], 1);
        atomicAdd(&hc[col[e]], 1);
    }
}

__device__ __forceinline__ int blk_exscan(int v, int t, int* ws) {
    int inc = v;
    #pragma unroll
    for (int o = 1; o < 64; o <<= 1) {
        int u = __shfl_up(inc, o);
        if ((t & 63) >= o) inc += u;
    }
    int w = t >> 6;
    if ((t & 63) == 63) ws[w] = inc;
    __syncthreads();
    int off = 0;
    for (int i = 0; i < w; ++i) off += ws[i];
    return off + inc - v;
}

__global__ void k_scan1(const int* __restrict__ h, int* __restrict__ part, int n) {
    __shared__ int ws[8];
    int t = threadIdx.x;
    int i = blockIdx.x * 256 + t;
    int v = (i < n) ? h[i] : 0;
    #pragma unroll
    for (int o = 32; o > 0; o >>= 1) v += __shfl_down(v, o);
    if ((t & 63) == 0) ws[t >> 6] = v;
    __syncthreads();
    if (t == 0) part[blockIdx.x] = ws[0] + ws[1] + ws[2] + ws[3];
}

__global__ void k_scan2(int* __restrict__ part, int nb) {
    __shared__ int ws[8];
    int t = threadIdx.x;
    int v = (t < nb) ? part[t] : 0;
    int e = blk_exscan(v, t, ws);
    if (t < nb) part[t] = e;
}

__global__ void k_scan3(const int* __restrict__ h, const int* __restrict__ part,
                        int* __restrict__ ptr, int n) {
    __shared__ int ws[8];
    int t = threadIdx.x;
    int i = blockIdx.x * 256 + t;
    int v = (i < n) ? h[i] : 0;
    int e = blk_exscan(v, t, ws);
    if (i <= n) ptr[i] = part[blockIdx.x] + e;
}

// fill: col-CSR rows (crows) + packed row-CSR (col, colCSRpos)
__global__ void k_fill(const int* __restrict__ row, const int* __restrict__ col,
                       const int* __restrict__ cptr, const int* __restrict__ rptr,
                       int* __restrict__ cntc, int* __restrict__ cntr,
                       int* __restrict__ crows, int2* __restrict__ rpack, int E) {
    int e = blockIdx.x * blockDim.x + threadIdx.x;
    if (e >= E) return;
    int r = row[e], c = col[e];
    int cp = cptr[c] + atomicAdd(&cntc[c], 1);
    int rp = rptr[r] + atomicAdd(&cntr[r], 1);
    crows[cp] = r;
    rpack[rp] = make_int2(c, cp);
}

// ============================ GEMM + fused attention scores ============================
// 64-row tile, full 128 cols, K tiled 2x64. 256 threads; thread = 4 rows x 8 cols.
// xs transposed [k][r] with XOR swizzle. Epilogue: sI = xw@a_i, sJ = xw@a_j.

__global__ __launch_bounds__(256) void k_gemm(const float* __restrict__ in,
                                              const float* __restrict__ W,
                                              const float* __restrict__ att,
                                              float* __restrict__ xw,
                                              float* __restrict__ sI,
                                              float* __restrict__ sJ,
                                              int nrows, int ntiles) {
    __shared__ float xs[128 * 64];
    __shared__ float Wl[64 * 128];
    __shared__ float sred[2][4][64];
    const int t = threadIdx.x;
    const int rg = t & 15;   // row group: rows 4*rg .. 4*rg+3
    const int cg = t >> 4;   // col group: cols 8*cg .. 8*cg+7
    const int w  = t >> 6;

    float ai8[8], aj8[8];
    *(float4*)&ai8[0] = *(const float4*)&att[cg * 8];
    *(float4*)&ai8[4] = *(const float4*)&att[cg * 8 + 4];
    *(float4*)&aj8[0] = *(const float4*)&att[HD + cg * 8];
    *(float4*)&aj8[4] = *(const float4*)&att[HD + cg * 8 + 4];

    for (int tile = blockIdx.x; tile < ntiles; tile += gridDim.x) {
        const int r0 = tile << 6;
        __syncthreads();   // protect xs/Wl/sred against previous iteration's readers
        #pragma unroll
        for (int it = 0; it < 8; ++it) {
            int q = t + (it << 8);      // 0..2047
            int r = q >> 5;             // 0..63
            int kq = q & 31;            // k-quad 0..31
            int gr = r0 + r;
            float4 v = make_float4(0.f, 0.f, 0.f, 0.f);
            if (gr < nrows) v = *(const float4*)&in[(size_t)gr * HD + (kq << 2)];
            int rq = r >> 2, rl = r & 3;
            const float* pv = (const float*)&v;
            int fk = kq & 15;
            #pragma unroll
            for (int j = 0; j < 4; ++j) {
                int k = (kq << 2) + j;
                xs[(k << 6) + (((rq ^ fk) << 2) | rl)] = pv[j];
            }
        }
        float acc[4][8];
        #pragma unroll
        for (int i = 0; i < 4; ++i)
            #pragma unroll
            for (int j = 0; j < 8; ++j) acc[i][j] = 0.f;

        for (int kt = 0; kt < 2; ++kt) {
            __syncthreads();
            #pragma unroll
            for (int it = 0; it < 8; ++it) {
                int q = (t + (it << 8)) << 2;
                *(float4*)&Wl[q] = *(const float4*)&W[(size_t)(kt << 6) * HD + q];
            }
            __syncthreads();
            #pragma unroll 8
            for (int kk = 0; kk < 64; ++kk) {
                int fk = kk >> 2;
                float4 a  = *(const float4*)&xs[(((kt << 6) + kk) << 6) + ((rg ^ fk) << 2)];
                float4 b0 = *(const float4*)&Wl[(kk << 7) + (cg << 3)];
                float4 b1 = *(const float4*)&Wl[(kk << 7) + (cg << 3) + 4];
                const float* ap  = (const float*)&a;
                const float* b0p = (const float*)&b0;
                const float* b1p = (const float*)&b1;
                #pragma unroll
                for (int i = 0; i < 4; ++i) {
                    #pragma unroll
                    for (int j = 0; j < 4; ++j) {
                        acc[i][j]     += ap[i] * b0p[j];
                        acc[i][j + 4] += ap[i] * b1p[j];
                    }
                }
            }
        }
        // C write
        #pragma unroll
        for (int i = 0; i < 4; ++i) {
            int gr = r0 + (rg << 2) + i;
            if (gr < nrows) {
                float4 o0 = make_float4(acc[i][0], acc[i][1], acc[i][2], acc[i][3]);
                float4 o1 = make_float4(acc[i][4], acc[i][5], acc[i][6], acc[i][7]);
                *(float4*)&xw[(size_t)gr * HD + (cg << 3)]     = o0;
                *(float4*)&xw[(size_t)gr * HD + (cg << 3) + 4] = o1;
            }
        }
        // fused attention-score epilogue
        float p4[4], q4[4];
        #pragma unroll
        for (int i = 0; i < 4; ++i) {
            float p = 0.f, q = 0.f;
            #pragma unroll
            for (int j = 0; j < 8; ++j) { p += acc[i][j] * ai8[j]; q += acc[i][j] * aj8[j]; }
            p4[i] = p; q4[i] = q;
        }
        #pragma unroll
        for (int o = 16; o <= 32; o <<= 1) {
            #pragma unroll
            for (int i = 0; i < 4; ++i) {
                p4[i] += __shfl_xor(p4[i], o);
                q4[i] += __shfl_xor(q4[i], o);
            }
        }
        if ((t & 63) < 16) {
            #pragma unroll
            for (int i = 0; i < 4; ++i) {
                sred[0][w][(rg << 2) + i] = p4[i];
                sred[1][w][(rg << 2) + i] = q4[i];
            }
        }
        __syncthreads();
        if (t < 64) {
            int gr = r0 + t;
            if (gr < nrows) {
                sI[gr] = sred[0][0][t] + sred[0][1][t] + sred[0][2][t] + sred[0][3][t];
                sJ[gr] = sred[1][0][t] + sred[1][1][t] + sred[1][2][t] + sred[1][3][t];
            }
        }
    }
}

// ============================ fused softmax + edge_feat ============================
// one wave per hyperedge c: wave-parallel softmax over the segment (alpha kept in
// registers, broadcast via shfl), then ef[c] = Binv * sum alpha * xw[row].

__global__ __launch_bounds__(256) void k_efsm(const float* __restrict__ sI,
                                              const float* __restrict__ sJ,
                                              const int* __restrict__ cptr,
                                              const int* __restrict__ crows,
                                              float* __restrict__ alpha,
                                              const float* __restrict__ xw,
                                              float* __restrict__ ef, int n) {
    int c = blockIdx.x * 4 + (threadIdx.x >> 6);
    if (c >= n) return;
    int l = threadIdx.x & 63;
    int p0 = cptr[c], p1 = cptr[c + 1];
    int deg = p1 - p0;
    size_t efb = (size_t)c * HD + 2 * l;
    if (deg == 0) {
        *(float2*)&ef[efb] = make_float2(0.f, 0.f);
        return;
    }
    float sj = sJ[c];
    float ax = 0.f, ay = 0.f;
    if (deg <= 64) {
        int p = p0 + l;
        int r = 0;
        float lg = -1e30f;
        if (l < deg) {
            r = crows[p];
            float v = sI[r] + sj;
            lg = v >= 0.f ? v : NEG_SLOPE * v;
        }
        float mm = lg;
        #pragma unroll
        for (int o = 32; o > 0; o >>= 1) mm = fmaxf(mm, __shfl_xor(mm, o));
        float ev = (l < deg) ? __expf(lg - mm) : 0.f;
        float ss = ev;
        #pragma unroll
        for (int o = 32; o > 0; o >>= 1) ss += __shfl_xor(ss, o);
        float a = ev / (ss + 1e-16f);
        if (l < deg) alpha[p] = a;
        for (int k = 0; k < deg; ++k) {
            float av = __shfl(a, k);
            int   rv = __shfl(r, k);
            float2 v = *(const float2*)&xw[(size_t)rv * HD + 2 * l];
            ax += av * v.x; ay += av * v.y;
        }
    } else {
        // rare: chunked online softmax
        float m = -1e30f, s = 0.f;
        for (int base = p0; base < p1; base += 64) {
            int p = base + l;
            float lg = -1e30f;
            if (p < p1) {
                float v = sI[crows[p]] + sj;
                lg = v >= 0.f ? v : NEG_SLOPE * v;
            }
            float mm = lg;
            #pragma unroll
            for (int o = 32; o > 0; o >>= 1) mm = fmaxf(mm, __shfl_xor(mm, o));
            float newm = fmaxf(m, mm);
            float ev = (p < p1) ? __expf(lg - newm) : 0.f;
            float ss = ev;
            #pragma unroll
            for (int o = 32; o > 0; o >>= 1) ss += __shfl_xor(ss, o);
            s = s * __expf(m - newm) + ss;
            m = newm;
        }
        float inv = 1.f / (s + 1e-16f);
        for (int base = p0; base < p1; base += 64) {
            int p = base + l;
            float a = 0.f; int r = 0;
            if (p < p1) {
                r = crows[p];
                float v = sI[r] + sj;
                v = v >= 0.f ? v : NEG_SLOPE * v;
                a = __expf(v - m) * inv;
                alpha[p] = a;
            }
            int cnt = min(64, p1 - base);
            for (int k = 0; k < cnt; ++k) {
                float av = __shfl(a, k);
                int   rv = __shfl(r, k);
                float2 v = *(const float2*)&xw[(size_t)rv * HD + 2 * l];
                ax += av * v.x; ay += av * v.y;
            }
        }
    }
    float binv = 1.f / (float)deg;
    *(float2*)&ef[efb] = make_float2(ax * binv, ay * binv);
}

// ============================ out = prelu(Dinv * sum alpha*ef[col] + b (+resid)) ============================

__global__ __launch_bounds__(256) void k_out(const int* __restrict__ rptr,
                                             const int2* __restrict__ rpack,
                                             const float* __restrict__ alpha,
                                             const float* __restrict__ ef,
                                             const float* __restrict__ bias,
                                             const float* __restrict__ resid,
                                             const float* __restrict__ pa,
                                             float* __restrict__ out, int n) {
    int nd = blockIdx.x * 4 + (threadIdx.x >> 6);
    if (nd >= n) return;
    int l = threadIdx.x & 63;
    int p0 = rptr[nd], p1 = rptr[nd + 1];
    float ax = 0.f, ay = 0.f;
    for (int p = p0; p < p1; ++p) {
        int2 cc = rpack[p];
        float a = alpha[cc.y];
        float2 v = *(const float2*)&ef[(size_t)cc.x * HD + 2 * l];
        ax += a * v.x; ay += a * v.y;
    }
    float dinv = (p1 > p0) ? 1.f / (float)(p1 - p0) : 0.f;
    int h = 2 * l;
    float vx = dinv * ax + bias[h];
    float vy = dinv * ay + bias[h + 1];
    size_t idx = (size_t)nd * HD + h;
    if (resid) { vx += resid[idx]; vy += resid[idx + 1]; }
    float s = pa[0];
    vx = vx >= 0.f ? vx : s * vx;
    vy = vy >= 0.f ? vy : s * vy;
    out[idx] = vx; out[idx + 1] = vy;
}

// ============================ launch ============================

extern "C" void kernel_launch(void* const* d_in, const int* in_sizes, int n_in,
                              void* d_out, int out_size, void* d_ws, size_t ws_size,
                              hipStream_t stream) {
    const float* x    = (const float*)d_in[0];
    const int*   hei  = (const int*)d_in[1];
    const float* W1   = (const float*)d_in[2];
    const float* att1 = (const float*)d_in[3];
    const float* b1   = (const float*)d_in[4];
    const float* W2   = (const float*)d_in[5];
    const float* att2 = (const float*)d_in[6];
    const float* b2   = (const float*)d_in[7];
    const float* pa   = (const float*)d_in[8];

    const int NH = in_sizes[0];
    const int Nn = NH / HD;
    const int E  = in_sizes[1] / 2;
    const int* row = hei;
    const int* col = hei + E;
    float* out = (float*)d_out;

    // workspace carve-up
    char* ws = (char*)d_ws;
    float* xw      = (float*)ws;                       ws += (size_t)NH * 4;
    float* ef      = (float*)ws;                       ws += (size_t)NH * 4;
    float* alpha   = (float*)ws;                       ws += (size_t)E * 4;
    int*   crows   = (int*)ws;                         ws += (size_t)E * 4;
    int2*  rpack   = (int2*)ws;                        ws += (size_t)E * 8;
    int*   cptr    = (int*)ws;                         ws += (size_t)(Nn + 1) * 4;
    int*   rptr    = (int*)ws;                         ws += (size_t)(Nn + 1) * 4;
    int*   hists   = (int*)ws;                         ws += (size_t)4 * Nn * 4;  // hr, hc, cntr, cntc
    int*   part    = (int*)ws;                         ws += 512 * 4;
    float* sI      = (float*)ws;                       ws += (size_t)Nn * 4;
    float* sJ      = (float*)ws;                       ws += (size_t)Nn * 4;
    int* hr = hists, *hc = hists + Nn, *cntr = hists + 2 * Nn, *cntc = hists + 3 * Nn;

    const int TB = 256;
    dim3 blk(TB);
    dim3 gE((E + TB - 1) / TB);
    dim3 gW4((Nn + 3) / 4);              // wave-per-item kernels
    const int nb = (Nn + 1 + 255) / 256;
    const int ntiles = (Nn + 63) >> 6;
    dim3 gGemm(512);

    // ---- CSR build (shared by both layers) ----
    hipMemsetAsync(hists, 0, (size_t)4 * Nn * 4, stream);
    k_hist<<<gE, blk, 0, stream>>>(row, col, hr, hc, E);
    k_scan1<<<nb, blk, 0, stream>>>(hc, part, Nn);
    k_scan2<<<1, 512, 0, stream>>>(part, nb);
    k_scan3<<<nb, blk, 0, stream>>>(hc, part, cptr, Nn);
    k_scan1<<<nb, blk, 0, stream>>>(hr, part, Nn);
    k_scan2<<<1, 512, 0, stream>>>(part, nb);
    k_scan3<<<nb, blk, 0, stream>>>(hr, part, rptr, Nn);
    k_fill<<<gE, blk, 0, stream>>>(row, col, cptr, rptr, cntc, cntr, crows, rpack, E);

    // ---- layer 1 ----
    k_gemm<<<gGemm, blk, 0, stream>>>(x, W1, att1, xw, sI, sJ, Nn, ntiles);
    k_efsm<<<gW4, blk, 0, stream>>>(sI, sJ, cptr, crows, alpha, xw, ef, Nn);
    k_out<<<gW4, blk, 0, stream>>>(rptr, rpack, alpha, ef, b1, nullptr, pa, out, Nn);

    // ---- layer 2 (input = d_out, residual = x) ----
    k_gemm<<<gGemm, blk, 0, stream>>>(out, W2, att2, xw, sI, sJ, Nn, ntiles);
    k_efsm<<<gW4, blk, 0, stream>>>(sI, sJ, cptr, crows, alpha, xw, ef, Nn);
    k_out<<<gW4, blk, 0, stream>>>(rptr, rpack, alpha, ef, b2, x, pa, out, Nn);
}

// Round 6
// 573.007 us; speedup vs baseline: 4.1425x; 1.2794x over previous
//
#include <hip/hip_runtime.h>
#include <math.h>

#define HD 128
#define NEG_SLOPE 0.2f

// ============================ CSR build ============================
// k_hist: histogram both sides AND capture each edge's offset within its segment.

__global__ void k_hist(const int* __restrict__ row, const int* __restrict__ col,
                       int* __restrict__ hc, int* __restrict__ hr,
                       int* __restrict__ ocol, int* __restrict__ orow, int E) {
    int e = blockIdx.x * blockDim.x + threadIdx.x;
    if (e < E) {
        ocol[e] = atomicAdd(&hc[col[e]], 1);
        orow[e] = atomicAdd(&hr[row[e]], 1);
    }
}

__device__ __forceinline__ int blk_exscan(int v, int t, int* ws) {
    int inc = v;
    #pragma unroll
    for (int o = 1; o < 64; o <<= 1) {
        int u = __shfl_up(inc, o);
        if ((t & 63) >= o) inc += u;
    }
    int w = t >> 6;
    if ((t & 63) == 63) ws[w] = inc;
    __syncthreads();
    int off = 0;
    for (int i = 0; i < w; ++i) off += ws[i];
    return off + inc - v;
}

// scan over concatenated [hc | hr] (length n2 = 2N); scan3 splits into cptr / rptr.
__global__ void k_scan1(const int* __restrict__ h, int* __restrict__ part, int n2) {
    __shared__ int ws[4];
    int t = threadIdx.x;
    int i = blockIdx.x * 256 + t;
    int v = (i < n2) ? h[i] : 0;
    #pragma unroll
    for (int o = 32; o > 0; o >>= 1) v += __shfl_down(v, o);
    if ((t & 63) == 0) ws[t >> 6] = v;
    __syncthreads();
    if (t == 0) part[blockIdx.x] = ws[0] + ws[1] + ws[2] + ws[3];
}

__global__ __launch_bounds__(1024) void k_scan2(int* __restrict__ part, int nb) {
    __shared__ int ws[16];
    int t = threadIdx.x;
    int v = (t < nb) ? part[t] : 0;
    int e = blk_exscan(v, t, ws);
    if (t < nb) part[t] = e;
}

__global__ void k_scan3(const int* __restrict__ h, const int* __restrict__ part,
                        int* __restrict__ cptr, int* __restrict__ rptr,
                        int n1, int n2, int E) {
    __shared__ int ws[4];
    int t = threadIdx.x;
    int i = blockIdx.x * 256 + t;
    int v = (i < n2) ? h[i] : 0;
    int e = blk_exscan(v, t, ws);
    if (i <= n2) {
        int val = part[blockIdx.x] + e;
        if (i <= n1) cptr[i] = val;
        if (i >= n1) rptr[i - n1] = val - E;
    }
}

// pure scatter, no atomics
__global__ void k_fill(const int* __restrict__ row, const int* __restrict__ col,
                       const int* __restrict__ cptr, const int* __restrict__ rptr,
                       const int* __restrict__ ocol, const int* __restrict__ orow,
                       int* __restrict__ crows, int2* __restrict__ rpack, int E) {
    int e = blockIdx.x * blockDim.x + threadIdx.x;
    if (e >= E) return;
    int r = row[e], c = col[e];
    int cp = cptr[c] + ocol[e];
    int rp = rptr[r] + orow[e];
    crows[cp] = r;
    rpack[rp] = make_int2(c, cp);
}

// ============================ GEMM + fused attention scores ============================

__global__ __launch_bounds__(256) void k_gemm(const float* __restrict__ in,
                                              const float* __restrict__ W,
                                              const float* __restrict__ att,
                                              float* __restrict__ xw,
                                              float* __restrict__ sI,
                                              float* __restrict__ sJ,
                                              int nrows, int ntiles) {
    __shared__ float xs[128 * 64];
    __shared__ float Wl[64 * 128];
    __shared__ float sred[2][4][64];
    const int t = threadIdx.x;
    const int rg = t & 15;
    const int cg = t >> 4;
    const int w  = t >> 6;

    float ai8[8], aj8[8];
    *(float4*)&ai8[0] = *(const float4*)&att[cg * 8];
    *(float4*)&ai8[4] = *(const float4*)&att[cg * 8 + 4];
    *(float4*)&aj8[0] = *(const float4*)&att[HD + cg * 8];
    *(float4*)&aj8[4] = *(const float4*)&att[HD + cg * 8 + 4];

    for (int tile = blockIdx.x; tile < ntiles; tile += gridDim.x) {
        const int r0 = tile << 6;
        __syncthreads();
        #pragma unroll
        for (int it = 0; it < 8; ++it) {
            int q = t + (it << 8);
            int r = q >> 5;
            int kq = q & 31;
            int gr = r0 + r;
            float4 v = make_float4(0.f, 0.f, 0.f, 0.f);
            if (gr < nrows) v = *(const float4*)&in[(size_t)gr * HD + (kq << 2)];
            int rq = r >> 2, rl = r & 3;
            const float* pv = (const float*)&v;
            int fk = kq & 15;
            #pragma unroll
            for (int j = 0; j < 4; ++j) {
                int k = (kq << 2) + j;
                xs[(k << 6) + (((rq ^ fk) << 2) | rl)] = pv[j];
            }
        }
        float acc[4][8];
        #pragma unroll
        for (int i = 0; i < 4; ++i)
            #pragma unroll
            for (int j = 0; j < 8; ++j) acc[i][j] = 0.f;

        for (int kt = 0; kt < 2; ++kt) {
            __syncthreads();
            #pragma unroll
            for (int it = 0; it < 8; ++it) {
                int q = (t + (it << 8)) << 2;
                *(float4*)&Wl[q] = *(const float4*)&W[(size_t)(kt << 6) * HD + q];
            }
            __syncthreads();
            #pragma unroll 8
            for (int kk = 0; kk < 64; ++kk) {
                int fk = kk >> 2;
                float4 a  = *(const float4*)&xs[(((kt << 6) + kk) << 6) + ((rg ^ fk) << 2)];
                float4 b0 = *(const float4*)&Wl[(kk << 7) + (cg << 3)];
                float4 b1 = *(const float4*)&Wl[(kk << 7) + (cg << 3) + 4];
                const float* ap  = (const float*)&a;
                const float* b0p = (const float*)&b0;
                const float* b1p = (const float*)&b1;
                #pragma unroll
                for (int i = 0; i < 4; ++i) {
                    #pragma unroll
                    for (int j = 0; j < 4; ++j) {
                        acc[i][j]     += ap[i] * b0p[j];
                        acc[i][j + 4] += ap[i] * b1p[j];
                    }
                }
            }
        }
        #pragma unroll
        for (int i = 0; i < 4; ++i) {
            int gr = r0 + (rg << 2) + i;
            if (gr < nrows) {
                float4 o0 = make_float4(acc[i][0], acc[i][1], acc[i][2], acc[i][3]);
                float4 o1 = make_float4(acc[i][4], acc[i][5], acc[i][6], acc[i][7]);
                *(float4*)&xw[(size_t)gr * HD + (cg << 3)]     = o0;
                *(float4*)&xw[(size_t)gr * HD + (cg << 3) + 4] = o1;
            }
        }
        float p4[4], q4[4];
        #pragma unroll
        for (int i = 0; i < 4; ++i) {
            float p = 0.f, q = 0.f;
            #pragma unroll
            for (int j = 0; j < 8; ++j) { p += acc[i][j] * ai8[j]; q += acc[i][j] * aj8[j]; }
            p4[i] = p; q4[i] = q;
        }
        #pragma unroll
        for (int o = 16; o <= 32; o <<= 1) {
            #pragma unroll
            for (int i = 0; i < 4; ++i) {
                p4[i] += __shfl_xor(p4[i], o);
                q4[i] += __shfl_xor(q4[i], o);
            }
        }
        if ((t & 63) < 16) {
            #pragma unroll
            for (int i = 0; i < 4; ++i) {
                sred[0][w][(rg << 2) + i] = p4[i];
                sred[1][w][(rg << 2) + i] = q4[i];
            }
        }
        __syncthreads();
        if (t < 64) {
            int gr = r0 + t;
            if (gr < nrows) {
                sI[gr] = sred[0][0][t] + sred[0][1][t] + sred[0][2][t] + sred[0][3][t];
                sJ[gr] = sred[1][0][t] + sred[1][1][t] + sred[1][2][t] + sred[1][3][t];
            }
        }
    }
}

// ============================ fused softmax + edge_feat ============================

__global__ __launch_bounds__(256) void k_efsm(const float* __restrict__ sI,
                                              const float* __restrict__ sJ,
                                              const int* __restrict__ cptr,
                                              const int* __restrict__ crows,
                                              float* __restrict__ alpha,
                                              const float* __restrict__ xw,
                                              float* __restrict__ ef, int n) {
    int c = blockIdx.x * 4 + (threadIdx.x >> 6);
    if (c >= n) return;
    int l = threadIdx.x & 63;
    int p0 = cptr[c], p1 = cptr[c + 1];
    int deg = p1 - p0;
    size_t efb = (size_t)c * HD + 2 * l;
    if (deg == 0) {
        *(float2*)&ef[efb] = make_float2(0.f, 0.f);
        return;
    }
    float sj = sJ[c];
    float ax = 0.f, ay = 0.f;
    if (deg <= 64) {
        int p = p0 + l;
        int r = 0;
        float lg = -1e30f;
        if (l < deg) {
            r = crows[p];
            float v = sI[r] + sj;
            lg = v >= 0.f ? v : NEG_SLOPE * v;
        }
        float mm = lg;
        #pragma unroll
        for (int o = 32; o > 0; o >>= 1) mm = fmaxf(mm, __shfl_xor(mm, o));
        float ev = (l < deg) ? __expf(lg - mm) : 0.f;
        float ss = ev;
        #pragma unroll
        for (int o = 32; o > 0; o >>= 1) ss += __shfl_xor(ss, o);
        float a = ev / (ss + 1e-16f);
        if (l < deg) alpha[p] = a;
        int k = 0;
        for (; k + 4 <= deg; k += 4) {
            float a0 = __shfl(a, k),     a1 = __shfl(a, k + 1);
            float a2 = __shfl(a, k + 2), a3 = __shfl(a, k + 3);
            int   r0 = __shfl(r, k),     r1 = __shfl(r, k + 1);
            int   r2 = __shfl(r, k + 2), r3 = __shfl(r, k + 3);
            float2 v0 = *(const float2*)&xw[(size_t)r0 * HD + 2 * l];
            float2 v1 = *(const float2*)&xw[(size_t)r1 * HD + 2 * l];
            float2 v2 = *(const float2*)&xw[(size_t)r2 * HD + 2 * l];
            float2 v3 = *(const float2*)&xw[(size_t)r3 * HD + 2 * l];
            ax += a0 * v0.x + a1 * v1.x + a2 * v2.x + a3 * v3.x;
            ay += a0 * v0.y + a1 * v1.y + a2 * v2.y + a3 * v3.y;
        }
        for (; k < deg; ++k) {
            float av = __shfl(a, k);
            int   rv = __shfl(r, k);
            float2 v = *(const float2*)&xw[(size_t)rv * HD + 2 * l];
            ax += av * v.x; ay += av * v.y;
        }
    } else {
        float m = -1e30f, s = 0.f;
        for (int base = p0; base < p1; base += 64) {
            int p = base + l;
            float lg = -1e30f;
            if (p < p1) {
                float v = sI[crows[p]] + sj;
                lg = v >= 0.f ? v : NEG_SLOPE * v;
            }
            float mm = lg;
            #pragma unroll
            for (int o = 32; o > 0; o >>= 1) mm = fmaxf(mm, __shfl_xor(mm, o));
            float newm = fmaxf(m, mm);
            float ev = (p < p1) ? __expf(lg - newm) : 0.f;
            float ss = ev;
            #pragma unroll
            for (int o = 32; o > 0; o >>= 1) ss += __shfl_xor(ss, o);
            s = s * __expf(m - newm) + ss;
            m = newm;
        }
        float inv = 1.f / (s + 1e-16f);
        for (int base = p0; base < p1; base += 64) {
            int p = base + l;
            float a = 0.f; int r = 0;
            if (p < p1) {
                r = crows[p];
                float v = sI[r] + sj;
                v = v >= 0.f ? v : NEG_SLOPE * v;
                a = __expf(v - m) * inv;
                alpha[p] = a;
            }
            int cnt = min(64, p1 - base);
            for (int k = 0; k < cnt; ++k) {
                float av = __shfl(a, k);
                int   rv = __shfl(r, k);
                float2 v = *(const float2*)&xw[(size_t)rv * HD + 2 * l];
                ax += av * v.x; ay += av * v.y;
            }
        }
    }
    float binv = 1.f / (float)deg;
    *(float2*)&ef[efb] = make_float2(ax * binv, ay * binv);
}

// ============================ out = prelu(Dinv * sum alpha*ef[col] + b (+resid)) ============================
// per-lane preload of (alpha, col) per 64-chunk, shfl-broadcast, 4x unrolled gathers.

__global__ __launch_bounds__(256) void k_out(const int* __restrict__ rptr,
                                             const int2* __restrict__ rpack,
                                             const float* __restrict__ alpha,
                                             const float* __restrict__ ef,
                                             const float* __restrict__ bias,
                                             const float* __restrict__ resid,
                                             const float* __restrict__ pa,
                                             float* __restrict__ out, int n) {
    int nd = blockIdx.x * 4 + (threadIdx.x >> 6);
    if (nd >= n) return;
    int l = threadIdx.x & 63;
    int p0 = rptr[nd], p1 = rptr[nd + 1];
    float ax = 0.f, ay = 0.f;
    for (int base = p0; base < p1; base += 64) {
        int p = base + l;
        int cc = 0; float a = 0.f;
        if (p < p1) {
            int2 pk = rpack[p];
            cc = pk.x;
            a = alpha[pk.y];
        }
        int cnt = min(64, p1 - base);
        int k = 0;
        for (; k + 4 <= cnt; k += 4) {
            float a0 = __shfl(a, k),     a1 = __shfl(a, k + 1);
            float a2 = __shfl(a, k + 2), a3 = __shfl(a, k + 3);
            int   c0 = __shfl(cc, k),     c1 = __shfl(cc, k + 1);
            int   c2 = __shfl(cc, k + 2), c3 = __shfl(cc, k + 3);
            float2 v0 = *(const float2*)&ef[(size_t)c0 * HD + 2 * l];
            float2 v1 = *(const float2*)&ef[(size_t)c1 * HD + 2 * l];
            float2 v2 = *(const float2*)&ef[(size_t)c2 * HD + 2 * l];
            float2 v3 = *(const float2*)&ef[(size_t)c3 * HD + 2 * l];
            ax += a0 * v0.x + a1 * v1.x + a2 * v2.x + a3 * v3.x;
            ay += a0 * v0.y + a1 * v1.y + a2 * v2.y + a3 * v3.y;
        }
        for (; k < cnt; ++k) {
            float av = __shfl(a, k);
            int   cv = __shfl(cc, k);
            float2 v = *(const float2*)&ef[(size_t)cv * HD + 2 * l];
            ax += av * v.x; ay += av * v.y;
        }
    }
    float dinv = (p1 > p0) ? 1.f / (float)(p1 - p0) : 0.f;
    int h = 2 * l;
    float vx = dinv * ax + bias[h];
    float vy = dinv * ay + bias[h + 1];
    size_t idx = (size_t)nd * HD + h;
    if (resid) { vx += resid[idx]; vy += resid[idx + 1]; }
    float s = pa[0];
    vx = vx >= 0.f ? vx : s * vx;
    vy = vy >= 0.f ? vy : s * vy;
    out[idx] = vx; out[idx + 1] = vy;
}

// ============================ launch ============================

extern "C" void kernel_launch(void* const* d_in, const int* in_sizes, int n_in,
                              void* d_out, int out_size, void* d_ws, size_t ws_size,
                              hipStream_t stream) {
    const float* x    = (const float*)d_in[0];
    const int*   hei  = (const int*)d_in[1];
    const float* W1   = (const float*)d_in[2];
    const float* att1 = (const float*)d_in[3];
    const float* b1   = (const float*)d_in[4];
    const float* W2   = (const float*)d_in[5];
    const float* att2 = (const float*)d_in[6];
    const float* b2   = (const float*)d_in[7];
    const float* pa   = (const float*)d_in[8];

    const int NH = in_sizes[0];
    const int Nn = NH / HD;
    const int E  = in_sizes[1] / 2;
    const int* row = hei;
    const int* col = hei + E;
    float* out = (float*)d_out;

    // workspace carve-up
    char* ws = (char*)d_ws;
    float* xw      = (float*)ws;                       ws += (size_t)NH * 4;
    float* ef      = (float*)ws;                       ws += (size_t)NH * 4;
    float* alpha   = (float*)ws;                       ws += (size_t)E * 4;
    int*   crows   = (int*)ws;                         ws += (size_t)E * 4;
    int2*  rpack   = (int2*)ws;                        ws += (size_t)E * 8;
    int*   cptr    = (int*)ws;                         ws += (size_t)(Nn + 1) * 4;
    int*   rptr    = (int*)ws;                         ws += (size_t)(Nn + 1) * 4;
    int*   hists   = (int*)ws;                         ws += (size_t)2 * Nn * 4;  // hc, hr
    int*   part    = (int*)ws;                         ws += 1024 * 4;
    float* sI      = (float*)ws;                       ws += (size_t)Nn * 4;
    float* sJ      = (float*)ws;                       ws += (size_t)Nn * 4;
    int* hc = hists, *hr = hists + Nn;
    int* ocol = (int*)alpha;      // dead until k_efsm (after k_fill)
    int* orow = (int*)d_out;      // dead until layer-1 k_out (fully overwritten)

    const int TB = 256;
    dim3 blk(TB);
    dim3 gE((E + TB - 1) / TB);
    dim3 gW4((Nn + 3) / 4);
    const int n2 = 2 * Nn;
    const int nb = (n2 + 1 + 255) / 256;   // scan blocks (covers n2+1 outputs)
    const int ntiles = (Nn + 63) >> 6;
    dim3 gGemm(512);

    // ---- CSR build (shared by both layers) ----
    hipMemsetAsync(hists, 0, (size_t)n2 * 4, stream);
    k_hist<<<gE, blk, 0, stream>>>(row, col, hc, hr, ocol, orow, E);
    k_scan1<<<nb, blk, 0, stream>>>(hists, part, n2);
    k_scan2<<<1, 1024, 0, stream>>>(part, nb);
    k_scan3<<<nb, blk, 0, stream>>>(hists, part, cptr, rptr, Nn, n2, E);
    k_fill<<<gE, blk, 0, stream>>>(row, col, cptr, rptr, ocol, orow, crows, rpack, E);

    // ---- layer 1 ----
    k_gemm<<<gGemm, blk, 0, stream>>>(x, W1, att1, xw, sI, sJ, Nn, ntiles);
    k_efsm<<<gW4, blk, 0, stream>>>(sI, sJ, cptr, crows, alpha, xw, ef, Nn);
    k_out<<<gW4, blk, 0, stream>>>(rptr, rpack, alpha, ef, b1, nullptr, pa, out, Nn);

    // ---- layer 2 (input = d_out, residual = x) ----
    k_gemm<<<gGemm, blk, 0, stream>>>(out, W2, att2, xw, sI, sJ, Nn, ntiles);
    k_efsm<<<gW4, blk, 0, stream>>>(sI, sJ, cptr, crows, alpha, xw, ef, Nn);
    k_out<<<gW4, blk, 0, stream>>>(rptr, rpack, alpha, ef, b2, x, pa, out, Nn);
}